// Round 13
// baseline (6563.065 us; speedup 1.0000x reference)
//
#include <hip/hip_runtime.h>

// k-means (Lloyd), N=500000 D=64 K=256 ITERS=10, fp32.
// Round 13: latency/convoy fixes. r8(2 waves/SIMD)=236us == r12(4 waves)=232us
// proved occupancy isn't the lever; the per-group serial chain + lockstep
// convoy is. Changes vs r12 (numerics identical):
//  - ping-pong prefetch: next group's x loads issued before current group's
//    MFMA/score phase (first load before the staging barrier).
//  - per-wave tile rotation ((tt+wv)&15): waves touch different chi regions
//    -> de-convoys the LDS pipe. Result order-independent (ties -> refine).
//  - v_cvt_pk_bf16_f32 (RNE) for x hi/lo conversion: ~3x fewer VALU ops.
//  - s_setprio(1) around the MFMA cluster.

#define D 64
#define K 256
#define ITERS 10
#define BLOCK 1024
#define NB_MAX 256
#define EPS 2e-2f
#define SPAD 66
#define PART_STRIDE (K * D + K)   // 16640 floats per block partial
// LDS: chi 32KB + clo 32KB + csq 1KB + sums(padded) 66KB + cnt 1KB = 132KB
#define SMEM_BYTES (32768 * 2 + (256 + 256 * SPAD + 256) * 4)

typedef __attribute__((ext_vector_type(8))) short bf16x8;
typedef __attribute__((ext_vector_type(4))) float f32x4;
typedef __attribute__((ext_vector_type(4))) short short4v;
typedef __attribute__((ext_vector_type(4))) unsigned int u32x4;

__device__ __forceinline__ unsigned short f2bf(float f) {
    unsigned u = __builtin_bit_cast(unsigned, f);
    u = u + 0x7FFFu + ((u >> 16) & 1u);   // RNE
    return (unsigned short)(u >> 16);
}
__device__ __forceinline__ float bf2f(unsigned short h) {
    unsigned u = ((unsigned)h) << 16;
    return __builtin_bit_cast(float, u);
}
// dst[15:0] = bf16_rne(a), dst[31:16] = bf16_rne(b)
__device__ __forceinline__ unsigned cvt_pk(float a, float b) {
    unsigned r;
    asm("v_cvt_pk_bf16_f32 %0, %1, %2" : "=v"(r) : "v"(a), "v"(b));
    return r;
}

// ---------------------------------------------------------------------------
__global__ void init_gather(const float* __restrict__ x,
                            const int* __restrict__ idx,
                            float* __restrict__ cent,
                            float* __restrict__ csq) {
    int k = blockIdx.x;
    int d = threadIdx.x;
    float v = x[(size_t)idx[k] * D + d];
    cent[k * D + d] = v;
    float s = v * v;
    #pragma unroll
    for (int off = 32; off > 0; off >>= 1) s += __shfl_down(s, off);
    if (d == 0) csq[k] = s;
}

// ---------------------------------------------------------------------------
// convert + MFMA(rotated tiles) + argmin/refine + owner-lane LDS accumulate
// for one 16-point group. Numerics identical to rounds 6-12.
__device__ __forceinline__ void process_group(
        const float (&xf)[16], int g, int base, int lim,
        int c15, int g4, int wv,
        const short* __restrict__ chi, const short* __restrict__ clo,
        const float* __restrict__ s_csq, float* __restrict__ s_sums,
        float* __restrict__ s_cnt,
        const float* __restrict__ x, const float* __restrict__ cent) {
    int prow = base + g * 16 + c15;
    const bool vA = prow < lim;
    const float* xr = x + (size_t)(vA ? prow : (lim - 1)) * D;

    // ---- hi/lo bf16 fragments via v_cvt_pk (RNE) ----
    bf16x8 bh[2], bl[2];
    #pragma unroll
    for (int s = 0; s < 2; ++s) {
        u32x4 h4, l4;
        #pragma unroll
        for (int e2 = 0; e2 < 4; ++e2) {
            float a = xf[s * 8 + 2 * e2], b = xf[s * 8 + 2 * e2 + 1];
            unsigned hw = cvt_pk(a, b);
            h4[e2] = hw;
            float ha = bf2f((unsigned short)(hw & 0xFFFFu));
            float hb = bf2f((unsigned short)(hw >> 16));
            l4[e2] = cvt_pk(a - ha, b - hb);
        }
        bh[s] = __builtin_bit_cast(bf16x8, h4);
        bl[s] = __builtin_bit_cast(bf16x8, l4);
    }

    // ---- 16 cent-tiles of MFMA, wave-rotated order ----
    f32x4 acc[16];
    __builtin_amdgcn_s_setprio(1);
    #pragma unroll
    for (int tt = 0; tt < 16; ++tt) {
        int ta = (tt + wv) & 15;
        f32x4 z = {0.f, 0.f, 0.f, 0.f};
        acc[tt] = z;
        #pragma unroll
        for (int s = 0; s < 2; ++s) {
            int ai = (((s * 4 + g4) * 256) + ta * 16 + c15) * 8;
            bf16x8 ah = *(const bf16x8*)&chi[ai];
            bf16x8 al = *(const bf16x8*)&clo[ai];
            acc[tt] = __builtin_amdgcn_mfma_f32_16x16x32_bf16(ah, bh[s], acc[tt], 0, 0, 0);
            acc[tt] = __builtin_amdgcn_mfma_f32_16x16x32_bf16(ah, bl[s], acc[tt], 0, 0, 0);
            acc[tt] = __builtin_amdgcn_mfma_f32_16x16x32_bf16(al, bh[s], acc[tt], 0, 0, 0);
        }
    }
    __builtin_amdgcn_s_setprio(0);

    // ---- pass 1: global approx min (order-invariant value) ----
    float gmin = 3.4e38f;
    int gidx = 0;
    #pragma unroll
    for (int tt = 0; tt < 16; ++tt) {
        int ta = (tt + wv) & 15;
        f32x4 q = *(const f32x4*)&s_csq[ta * 16 + (g4 << 2)];
        #pragma unroll
        for (int r = 0; r < 4; ++r) {
            float sc = acc[tt][r] + q[r];
            int m = ta * 16 + (g4 << 2) + r;
            if (sc < gmin) { gmin = sc; gidx = m; }
        }
    }
    #pragma unroll
    for (int off = 16; off <= 32; off <<= 1) {
        float so = __shfl_xor(gmin, off);
        int io = __shfl_xor(gidx, off);
        if (so < gmin || (so == gmin && io < gidx)) { gmin = so; gidx = io; }
    }
    // ---- pass 2: candidate mask vs FINAL min ----
    unsigned long long cmask = 0;
    #pragma unroll
    for (int tt = 0; tt < 16; ++tt) {
        int ta = (tt + wv) & 15;
        f32x4 q = *(const f32x4*)&s_csq[ta * 16 + (g4 << 2)];
        #pragma unroll
        for (int r = 0; r < 4; ++r) {
            float sc = acc[tt][r] + q[r];
            if (sc <= gmin + EPS) cmask |= 1ull << (ta * 4 + r);
        }
    }
    int nb_ = __popcll(cmask);
    nb_ += __shfl_xor(nb_, 16);
    nb_ += __shfl_xor(nb_, 32);

    int bk = gidx;
    if (__any(nb_ >= 2)) {
        // exact fp32 refine: reference formula, fp32 centroids (r6 numerics)
        float xsq = 0.0f;
        #pragma unroll
        for (int d = 0; d < D; ++d) xsq += xr[d] * xr[d];
        float eb = 3.4e38f;
        int em = 0x7fffffff;
        unsigned long long mm = cmask;
        while (mm) {
            int b = __ffsll((unsigned long long)mm) - 1;
            mm &= mm - 1;
            int m = ((b >> 2) << 4) + (g4 << 2) + (b & 3);
            const float* cr = cent + m * D;
            float dot = 0.0f;
            #pragma unroll
            for (int d4 = 0; d4 < D; d4 += 4) {
                float4 c4 = *(const float4*)(cr + d4);
                dot += c4.x * xr[d4 + 0];
                dot += c4.y * xr[d4 + 1];
                dot += c4.z * xr[d4 + 2];
                dot += c4.w * xr[d4 + 3];
            }
            float es = xsq - 2.0f * dot + s_csq[m];
            if (es < eb || (es == eb && m < em)) { eb = es; em = m; }
        }
        #pragma unroll
        for (int off = 16; off <= 32; off <<= 1) {
            float so = __shfl_xor(eb, off);
            int io = __shfl_xor(em, off);
            if (so < eb || (so == eb && io < em)) { eb = so; em = io; }
        }
        bk = em;
    }

    // ---- owner-lane accumulate to LDS ----
    if (vA) {
        #pragma unroll
        for (int s = 0; s < 2; ++s) {
            #pragma unroll
            for (int e = 0; e < 8; ++e)
                atomicAdd(&s_sums[bk * SPAD + s * 32 + g4 * 8 + e],
                          xf[s * 8 + e]);
        }
        if (g4 == 0) atomicAdd(&s_cnt[bk], 1.0f);
    }
}

// ---------------------------------------------------------------------------
// fused assign (MFMA + exact refine) + owner-lane LDS accumulate.
// chi/clo LDS layout: [8 k-chunks][256 cents][8 elems] bf16 of (-2*c).
__global__ __launch_bounds__(BLOCK, 4) void assign_mfma(
        const float* __restrict__ x,
        const float* __restrict__ cent,
        const float* __restrict__ csq_g,
        float* __restrict__ parts,
        int N, int ppb) {
    extern __shared__ char smem[];
    short* chi = (short*)smem;                       // 16384 shorts
    short* clo = chi + 16384;                        // 16384 shorts
    float* s_csq = (float*)(clo + 16384);            // 256
    float* s_sums = s_csq + 256;                     // 256*SPAD
    float* s_cnt = s_sums + 256 * SPAD;              // 256

    const int tid = threadIdx.x;
    const int wv = tid >> 6;          // 0..15
    const int lane = tid & 63;
    const int c15 = lane & 15;        // point-in-group / B col
    const int g4 = lane >> 4;         // k-chunk slice / cent quadrant

    const int base = blockIdx.x * ppb;
    int lim = base + ppb;
    if (lim > N) lim = N;
    const int ngroups = (lim > base) ? ((lim - base + 15) >> 4) : 0;

#define LOADX(dst, grp)                                                     \
    {                                                                       \
        int pr_ = base + (grp) * 16 + c15;                                  \
        const float* xp_ =                                                  \
            x + (size_t)((pr_ < lim) ? pr_ : (lim - 1)) * D + g4 * 8;       \
        float4 t0_ = *(const float4*)(xp_);                                 \
        float4 t1_ = *(const float4*)(xp_ + 4);                             \
        float4 t2_ = *(const float4*)(xp_ + 32);                            \
        float4 t3_ = *(const float4*)(xp_ + 36);                            \
        dst[0] = t0_.x;  dst[1] = t0_.y;  dst[2] = t0_.z;  dst[3] = t0_.w;  \
        dst[4] = t1_.x;  dst[5] = t1_.y;  dst[6] = t1_.z;  dst[7] = t1_.w;  \
        dst[8] = t2_.x;  dst[9] = t2_.y;  dst[10] = t2_.z; dst[11] = t2_.w; \
        dst[12] = t3_.x; dst[13] = t3_.y; dst[14] = t3_.z; dst[15] = t3_.w; \
    }

    // ---- prefetch first group's x before staging (hides under staging) ----
    float xfA[16], xfB[16];
    if (wv < ngroups) LOADX(xfA, wv);

    // ---- stage centroids as -2c hi/lo bf16; zero LDS partials ----
    for (int i = tid; i < (K * D) / 4; i += BLOCK) {
        float4 c4 = ((const float4*)cent)[i];
        int elem = i * 4;
        int m = elem >> 6;
        int k0 = elem & 63;
        int g = k0 >> 3, e0 = k0 & 7;
        float cv[4] = {c4.x, c4.y, c4.z, c4.w};
        short4v hv, lv;
        #pragma unroll
        for (int j = 0; j < 4; ++j) {
            float v = -2.0f * cv[j];
            unsigned short h = f2bf(v);
            hv[j] = (short)h;
            lv[j] = (short)f2bf(v - bf2f(h));
        }
        int dst = (g * 256 + m) * 8 + e0;
        *(short4v*)&chi[dst] = hv;
        *(short4v*)&clo[dst] = lv;
    }
    if (tid < K) s_csq[tid] = csq_g[tid];
    for (int i = tid; i < 256 * SPAD; i += BLOCK) s_sums[i] = 0.0f;
    if (tid < K) s_cnt[tid] = 0.0f;
    __syncthreads();

    // ---- pipelined main loop: 2 groups per iteration, prefetch depth 1 ----
    #pragma unroll 1
    for (int g = wv; g < ngroups; g += 32) {
        int gB = g + 16;
        bool hB = gB < ngroups;
        if (hB) LOADX(xfB, gB);
        process_group(xfA, g, base, lim, c15, g4, wv,
                      chi, clo, s_csq, s_sums, s_cnt, x, cent);
        if (hB) {
            int gC = gB + 16;
            if (gC < ngroups) LOADX(xfA, gC);
            process_group(xfB, gB, base, lim, c15, g4, wv,
                          chi, clo, s_csq, s_sums, s_cnt, x, cent);
        }
    }
#undef LOADX

    __syncthreads();
    // ---- flush block partials (unpad) ----
    float* part = parts + (size_t)blockIdx.x * PART_STRIDE;
    for (int i = tid; i < K * D; i += BLOCK) {
        int k = i >> 6, d = i & 63;
        part[i] = s_sums[k * SPAD + d];
    }
    if (tid < K) part[K * D + tid] = s_cnt[tid];
}

// ---------------------------------------------------------------------------
// fused reduce + finalize: one cent per block, 256 threads (4 slices x 64 dims)
__global__ void finalize2(float* __restrict__ cent,
                          const float* __restrict__ parts,
                          float* __restrict__ csq_g,
                          int nb) {
    __shared__ float tmp[4][64];
    __shared__ float tcnt[4];
    int k = blockIdx.x;
    int sl = threadIdx.x >> 6;
    int d = threadIdx.x & 63;
    float s = 0.0f, c = 0.0f;
    for (int b = sl; b < nb; b += 4) {
        const float* pb = parts + (size_t)b * PART_STRIDE;
        s += pb[k * D + d];
        c += pb[K * D + k];
    }
    tmp[sl][d] = s;
    if (d == 0) tcnt[sl] = c;
    __syncthreads();
    if (sl == 0) {
        float st = tmp[0][d] + tmp[1][d] + tmp[2][d] + tmp[3][d];
        float ct = tcnt[0] + tcnt[1] + tcnt[2] + tcnt[3];
        float oldc = cent[k * D + d];
        float nc = (ct > 0.0f) ? (st / ct) : oldc;
        cent[k * D + d] = nc;
        float v = nc * nc;
        #pragma unroll
        for (int off = 32; off > 0; off >>= 1) v += __shfl_down(v, off);
        if (d == 0) csq_g[k] = v;
    }
}

// ---------------------------------------------------------------------------
extern "C" void kernel_launch(void* const* d_in, const int* in_sizes, int n_in,
                              void* d_out, int out_size, void* d_ws, size_t ws_size,
                              hipStream_t stream) {
    const float* x = (const float*)d_in[0];
    const int* init_idx = (const int*)d_in[1];

    int N = in_sizes[0] / D;

    float* cent = (float*)d_out;

    // ws layout: parts[nb][PART_STRIDE] | csq[K]
    int nb = NB_MAX;
    size_t need = ((size_t)NB_MAX * PART_STRIDE + K) * sizeof(float);
    if (ws_size < need) {
        size_t avail = (ws_size > (size_t)K * sizeof(float))
                           ? ws_size - (size_t)K * sizeof(float) : 0;
        nb = (int)(avail / (PART_STRIDE * sizeof(float)));
        if (nb < 1) nb = 1;
    }
    float* parts = (float*)d_ws;
    float* csq = parts + (size_t)nb * PART_STRIDE;

    hipFuncSetAttribute(reinterpret_cast<const void*>(assign_mfma),
                        hipFuncAttributeMaxDynamicSharedMemorySize, SMEM_BYTES);

    init_gather<<<dim3(K), dim3(64), 0, stream>>>(x, init_idx, cent, csq);

    int ppb = (N + nb - 1) / nb;
    for (int it = 0; it < ITERS; ++it) {
        assign_mfma<<<dim3(nb), dim3(BLOCK), SMEM_BYTES, stream>>>(
            x, cent, csq, parts, N, ppb);
        finalize2<<<dim3(K), dim3(256), 0, stream>>>(cent, parts, csq, nb);
    }
}

// Round 14
// 5026.847 us; speedup vs baseline: 1.3056x; 1.3056x over previous
//
#include <hip/hip_runtime.h>

// k-means (Lloyd), N=500000 D=64 K=256 ITERS=10, fp32.
// Round 14: r13's pipeline (ping-pong prefetch, cvt_pk, tile rotation,
// setprio) ported to the ONLY spill-free envelope measured: BLOCK=512,
// launch_bounds(512,1) (r7/r8: 108-128 VGPR, FETCH/WRITE ideal). r13's
// BLOCK=1024 hit the toolchain's hard 64-VGPR cap for 1024-thread blocks
// (seen in r9/r11/r12/r13) and the +32-float ping-pong exploded scratch
// traffic to 1.4GB. Live-reg audit here: acc64+frag16+xfA16+xfB16+~10=122.
// Numerics identical to rounds 6-13.

#define D 64
#define K 256
#define ITERS 10
#define BLOCK 512
#define NB_MAX 256
#define EPS 2e-2f
#define SPAD 66
#define PART_STRIDE (K * D + K)   // 16640 floats per block partial
// LDS: chi 32KB + clo 32KB + csq 1KB + sums(padded) 66KB + cnt 1KB = 132KB
#define SMEM_BYTES (32768 * 2 + (256 + 256 * SPAD + 256) * 4)

typedef __attribute__((ext_vector_type(8))) short bf16x8;
typedef __attribute__((ext_vector_type(4))) float f32x4;
typedef __attribute__((ext_vector_type(4))) short short4v;
typedef __attribute__((ext_vector_type(4))) unsigned int u32x4;

__device__ __forceinline__ unsigned short f2bf(float f) {
    unsigned u = __builtin_bit_cast(unsigned, f);
    u = u + 0x7FFFu + ((u >> 16) & 1u);   // RNE
    return (unsigned short)(u >> 16);
}
__device__ __forceinline__ float bf2f(unsigned short h) {
    unsigned u = ((unsigned)h) << 16;
    return __builtin_bit_cast(float, u);
}
// dst[15:0] = bf16_rne(a), dst[31:16] = bf16_rne(b)
__device__ __forceinline__ unsigned cvt_pk(float a, float b) {
    unsigned r;
    asm("v_cvt_pk_bf16_f32 %0, %1, %2" : "=v"(r) : "v"(a), "v"(b));
    return r;
}

// ---------------------------------------------------------------------------
__global__ void init_gather(const float* __restrict__ x,
                            const int* __restrict__ idx,
                            float* __restrict__ cent,
                            float* __restrict__ csq) {
    int k = blockIdx.x;
    int d = threadIdx.x;
    float v = x[(size_t)idx[k] * D + d];
    cent[k * D + d] = v;
    float s = v * v;
    #pragma unroll
    for (int off = 32; off > 0; off >>= 1) s += __shfl_down(s, off);
    if (d == 0) csq[k] = s;
}

// ---------------------------------------------------------------------------
// convert + MFMA(rotated tiles) + argmin/refine + owner-lane LDS accumulate
// for one 16-point group. Numerics identical to rounds 6-13.
__device__ __forceinline__ void process_group(
        const float (&xf)[16], int g, int base, int lim,
        int c15, int g4, int rot,
        const short* __restrict__ chi, const short* __restrict__ clo,
        const float* __restrict__ s_csq, float* __restrict__ s_sums,
        float* __restrict__ s_cnt,
        const float* __restrict__ x, const float* __restrict__ cent) {
    int prow = base + g * 16 + c15;
    const bool vA = prow < lim;
    const float* xr = x + (size_t)(vA ? prow : (lim - 1)) * D;

    // ---- hi/lo bf16 fragments via v_cvt_pk (RNE) ----
    bf16x8 bh[2], bl[2];
    #pragma unroll
    for (int s = 0; s < 2; ++s) {
        u32x4 h4, l4;
        #pragma unroll
        for (int e2 = 0; e2 < 4; ++e2) {
            float a = xf[s * 8 + 2 * e2], b = xf[s * 8 + 2 * e2 + 1];
            unsigned hw = cvt_pk(a, b);
            h4[e2] = hw;
            float ha = bf2f((unsigned short)(hw & 0xFFFFu));
            float hb = bf2f((unsigned short)(hw >> 16));
            l4[e2] = cvt_pk(a - ha, b - hb);
        }
        bh[s] = __builtin_bit_cast(bf16x8, h4);
        bl[s] = __builtin_bit_cast(bf16x8, l4);
    }

    // ---- 16 cent-tiles of MFMA, wave-rotated order ----
    f32x4 acc[16];
    __builtin_amdgcn_s_setprio(1);
    #pragma unroll
    for (int tt = 0; tt < 16; ++tt) {
        int ta = (tt + rot) & 15;
        f32x4 z = {0.f, 0.f, 0.f, 0.f};
        acc[tt] = z;
        #pragma unroll
        for (int s = 0; s < 2; ++s) {
            int ai = (((s * 4 + g4) * 256) + ta * 16 + c15) * 8;
            bf16x8 ah = *(const bf16x8*)&chi[ai];
            bf16x8 al = *(const bf16x8*)&clo[ai];
            acc[tt] = __builtin_amdgcn_mfma_f32_16x16x32_bf16(ah, bh[s], acc[tt], 0, 0, 0);
            acc[tt] = __builtin_amdgcn_mfma_f32_16x16x32_bf16(ah, bl[s], acc[tt], 0, 0, 0);
            acc[tt] = __builtin_amdgcn_mfma_f32_16x16x32_bf16(al, bh[s], acc[tt], 0, 0, 0);
        }
    }
    __builtin_amdgcn_s_setprio(0);

    // ---- pass 1: global approx min (order-invariant value) ----
    float gmin = 3.4e38f;
    int gidx = 0;
    #pragma unroll
    for (int tt = 0; tt < 16; ++tt) {
        int ta = (tt + rot) & 15;
        f32x4 q = *(const f32x4*)&s_csq[ta * 16 + (g4 << 2)];
        #pragma unroll
        for (int r = 0; r < 4; ++r) {
            float sc = acc[tt][r] + q[r];
            int m = ta * 16 + (g4 << 2) + r;
            if (sc < gmin) { gmin = sc; gidx = m; }
        }
    }
    #pragma unroll
    for (int off = 16; off <= 32; off <<= 1) {
        float so = __shfl_xor(gmin, off);
        int io = __shfl_xor(gidx, off);
        if (so < gmin || (so == gmin && io < gidx)) { gmin = so; gidx = io; }
    }
    // ---- pass 2: candidate mask vs FINAL min ----
    unsigned long long cmask = 0;
    #pragma unroll
    for (int tt = 0; tt < 16; ++tt) {
        int ta = (tt + rot) & 15;
        f32x4 q = *(const f32x4*)&s_csq[ta * 16 + (g4 << 2)];
        #pragma unroll
        for (int r = 0; r < 4; ++r) {
            float sc = acc[tt][r] + q[r];
            if (sc <= gmin + EPS) cmask |= 1ull << (ta * 4 + r);
        }
    }
    int nb_ = __popcll(cmask);
    nb_ += __shfl_xor(nb_, 16);
    nb_ += __shfl_xor(nb_, 32);

    int bk = gidx;
    if (__any(nb_ >= 2)) {
        // exact fp32 refine: reference formula, fp32 centroids (r6 numerics)
        float xsq = 0.0f;
        #pragma unroll
        for (int d = 0; d < D; ++d) xsq += xr[d] * xr[d];
        float eb = 3.4e38f;
        int em = 0x7fffffff;
        unsigned long long mm = cmask;
        while (mm) {
            int b = __ffsll((unsigned long long)mm) - 1;
            mm &= mm - 1;
            int m = ((b >> 2) << 4) + (g4 << 2) + (b & 3);
            const float* cr = cent + m * D;
            float dot = 0.0f;
            #pragma unroll
            for (int d4 = 0; d4 < D; d4 += 4) {
                float4 c4 = *(const float4*)(cr + d4);
                dot += c4.x * xr[d4 + 0];
                dot += c4.y * xr[d4 + 1];
                dot += c4.z * xr[d4 + 2];
                dot += c4.w * xr[d4 + 3];
            }
            float es = xsq - 2.0f * dot + s_csq[m];
            if (es < eb || (es == eb && m < em)) { eb = es; em = m; }
        }
        #pragma unroll
        for (int off = 16; off <= 32; off <<= 1) {
            float so = __shfl_xor(eb, off);
            int io = __shfl_xor(em, off);
            if (so < eb || (so == eb && io < em)) { eb = so; em = io; }
        }
        bk = em;
    }

    // ---- owner-lane accumulate to LDS ----
    if (vA) {
        #pragma unroll
        for (int s = 0; s < 2; ++s) {
            #pragma unroll
            for (int e = 0; e < 8; ++e)
                atomicAdd(&s_sums[bk * SPAD + s * 32 + g4 * 8 + e],
                          xf[s * 8 + e]);
        }
        if (g4 == 0) atomicAdd(&s_cnt[bk], 1.0f);
    }
}

// ---------------------------------------------------------------------------
// fused assign (MFMA + exact refine) + owner-lane LDS accumulate.
// chi/clo LDS layout: [8 k-chunks][256 cents][8 elems] bf16 of (-2*c).
__global__ __launch_bounds__(BLOCK, 1) void assign_mfma(
        const float* __restrict__ x,
        const float* __restrict__ cent,
        const float* __restrict__ csq_g,
        float* __restrict__ parts,
        int N, int ppb) {
    extern __shared__ char smem[];
    short* chi = (short*)smem;                       // 16384 shorts
    short* clo = chi + 16384;                        // 16384 shorts
    float* s_csq = (float*)(clo + 16384);            // 256
    float* s_sums = s_csq + 256;                     // 256*SPAD
    float* s_cnt = s_sums + 256 * SPAD;              // 256

    const int tid = threadIdx.x;
    const int wv = tid >> 6;          // 0..7
    const int lane = tid & 63;
    const int c15 = lane & 15;        // point-in-group / B col
    const int g4 = lane >> 4;         // k-chunk slice / cent quadrant
    const int rot = 2 * wv;           // tile rotation (8 waves over 16 tiles)

    const int base = blockIdx.x * ppb;
    int lim = base + ppb;
    if (lim > N) lim = N;
    const int ngroups = (lim > base) ? ((lim - base + 15) >> 4) : 0;

#define LOADX(dst, grp)                                                     \
    {                                                                       \
        int pr_ = base + (grp) * 16 + c15;                                  \
        const float* xp_ =                                                  \
            x + (size_t)((pr_ < lim) ? pr_ : (lim - 1)) * D + g4 * 8;       \
        float4 t0_ = *(const float4*)(xp_);                                 \
        float4 t1_ = *(const float4*)(xp_ + 4);                             \
        float4 t2_ = *(const float4*)(xp_ + 32);                            \
        float4 t3_ = *(const float4*)(xp_ + 36);                            \
        dst[0] = t0_.x;  dst[1] = t0_.y;  dst[2] = t0_.z;  dst[3] = t0_.w;  \
        dst[4] = t1_.x;  dst[5] = t1_.y;  dst[6] = t1_.z;  dst[7] = t1_.w;  \
        dst[8] = t2_.x;  dst[9] = t2_.y;  dst[10] = t2_.z; dst[11] = t2_.w; \
        dst[12] = t3_.x; dst[13] = t3_.y; dst[14] = t3_.z; dst[15] = t3_.w; \
    }

    // ---- prefetch first group's x before staging (hides under staging) ----
    float xfA[16], xfB[16];
    if (wv < ngroups) LOADX(xfA, wv);

    // ---- stage centroids as -2c hi/lo bf16; zero LDS partials ----
    for (int i = tid; i < (K * D) / 4; i += BLOCK) {
        float4 c4 = ((const float4*)cent)[i];
        int elem = i * 4;
        int m = elem >> 6;
        int k0 = elem & 63;
        int g = k0 >> 3, e0 = k0 & 7;
        float cv[4] = {c4.x, c4.y, c4.z, c4.w};
        short4v hv, lv;
        #pragma unroll
        for (int j = 0; j < 4; ++j) {
            float v = -2.0f * cv[j];
            unsigned short h = f2bf(v);
            hv[j] = (short)h;
            lv[j] = (short)f2bf(v - bf2f(h));
        }
        int dst = (g * 256 + m) * 8 + e0;
        *(short4v*)&chi[dst] = hv;
        *(short4v*)&clo[dst] = lv;
    }
    if (tid < K) s_csq[tid] = csq_g[tid];
    for (int i = tid; i < 256 * SPAD; i += BLOCK) s_sums[i] = 0.0f;
    if (tid < K) s_cnt[tid] = 0.0f;
    __syncthreads();

    // ---- pipelined main loop: 2 groups per iteration, prefetch depth 1 ----
    #pragma unroll 1
    for (int g = wv; g < ngroups; g += 16) {
        int gB = g + 8;
        bool hB = gB < ngroups;
        if (hB) LOADX(xfB, gB);
        process_group(xfA, g, base, lim, c15, g4, rot,
                      chi, clo, s_csq, s_sums, s_cnt, x, cent);
        if (hB) {
            int gC = gB + 8;
            if (gC < ngroups) LOADX(xfA, gC);
            process_group(xfB, gB, base, lim, c15, g4, rot,
                          chi, clo, s_csq, s_sums, s_cnt, x, cent);
        }
    }
#undef LOADX

    __syncthreads();
    // ---- flush block partials (unpad) ----
    float* part = parts + (size_t)blockIdx.x * PART_STRIDE;
    for (int i = tid; i < K * D; i += BLOCK) {
        int k = i >> 6, d = i & 63;
        part[i] = s_sums[k * SPAD + d];
    }
    if (tid < K) part[K * D + tid] = s_cnt[tid];
}

// ---------------------------------------------------------------------------
// fused reduce + finalize: one cent per block, 256 threads (4 slices x 64 dims)
__global__ void finalize2(float* __restrict__ cent,
                          const float* __restrict__ parts,
                          float* __restrict__ csq_g,
                          int nb) {
    __shared__ float tmp[4][64];
    __shared__ float tcnt[4];
    int k = blockIdx.x;
    int sl = threadIdx.x >> 6;
    int d = threadIdx.x & 63;
    float s = 0.0f, c = 0.0f;
    for (int b = sl; b < nb; b += 4) {
        const float* pb = parts + (size_t)b * PART_STRIDE;
        s += pb[k * D + d];
        c += pb[K * D + k];
    }
    tmp[sl][d] = s;
    if (d == 0) tcnt[sl] = c;
    __syncthreads();
    if (sl == 0) {
        float st = tmp[0][d] + tmp[1][d] + tmp[2][d] + tmp[3][d];
        float ct = tcnt[0] + tcnt[1] + tcnt[2] + tcnt[3];
        float oldc = cent[k * D + d];
        float nc = (ct > 0.0f) ? (st / ct) : oldc;
        cent[k * D + d] = nc;
        float v = nc * nc;
        #pragma unroll
        for (int off = 32; off > 0; off >>= 1) v += __shfl_down(v, off);
        if (d == 0) csq_g[k] = v;
    }
}

// ---------------------------------------------------------------------------
extern "C" void kernel_launch(void* const* d_in, const int* in_sizes, int n_in,
                              void* d_out, int out_size, void* d_ws, size_t ws_size,
                              hipStream_t stream) {
    const float* x = (const float*)d_in[0];
    const int* init_idx = (const int*)d_in[1];

    int N = in_sizes[0] / D;

    float* cent = (float*)d_out;

    // ws layout: parts[nb][PART_STRIDE] | csq[K]
    int nb = NB_MAX;
    size_t need = ((size_t)NB_MAX * PART_STRIDE + K) * sizeof(float);
    if (ws_size < need) {
        size_t avail = (ws_size > (size_t)K * sizeof(float))
                           ? ws_size - (size_t)K * sizeof(float) : 0;
        nb = (int)(avail / (PART_STRIDE * sizeof(float)));
        if (nb < 1) nb = 1;
    }
    float* parts = (float*)d_ws;
    float* csq = parts + (size_t)nb * PART_STRIDE;

    hipFuncSetAttribute(reinterpret_cast<const void*>(assign_mfma),
                        hipFuncAttributeMaxDynamicSharedMemorySize, SMEM_BYTES);

    init_gather<<<dim3(K), dim3(64), 0, stream>>>(x, init_idx, cent, csq);

    int ppb = (N + nb - 1) / nb;
    for (int it = 0; it < ITERS; ++it) {
        assign_mfma<<<dim3(nb), dim3(BLOCK), SMEM_BYTES, stream>>>(
            x, cent, csq, parts, N, ppb);
        finalize2<<<dim3(K), dim3(256), 0, stream>>>(cent, parts, csq, nb);
    }
}

// Round 15
// 2374.867 us; speedup vs baseline: 2.7636x; 2.1167x over previous
//
#include <hip/hip_runtime.h>

// k-means (Lloyd), N=500000 D=64 K=256 ITERS=10, fp32.
// Round 15: r12 base with EPS 2e-2 -> 2e-3. Wall analysis: per-group wall
// ~40k cyc vs ~2.6k visible chain, insensitive to occupancy/ILP, all pipes
// <20% -> the serial exact-refine branch (global cent loads, L1-thrashed) is
// the prime suspect; EPS=2e-2 made near-ties trigger it for most waves on
// this data (centroids cluster -> small score gaps). The 3-term hi/lo MFMA
// score error is ~3e-4 absolute, so EPS=2e-3 is still provably sound for
// the pruning and cuts the refine rate ~20x. Single-variable change.

#define D 64
#define K 256
#define ITERS 10
#define BLOCK 1024
#define NB_MAX 256
#define EPS 2e-3f
#define SPAD 66
#define PART_STRIDE (K * D + K)   // 16640 floats per block partial
// LDS: chi 32KB + clo 32KB + csq 1KB + sums(padded) 66KB + cnt 1KB = 132KB
#define SMEM_BYTES (32768 * 2 + (256 + 256 * SPAD + 256) * 4)

typedef __attribute__((ext_vector_type(8))) short bf16x8;
typedef __attribute__((ext_vector_type(4))) float f32x4;
typedef __attribute__((ext_vector_type(4))) short short4v;

__device__ __forceinline__ unsigned short f2bf(float f) {
    unsigned u = __builtin_bit_cast(unsigned, f);
    u = u + 0x7FFFu + ((u >> 16) & 1u);   // RNE
    return (unsigned short)(u >> 16);
}
__device__ __forceinline__ float bf2f(unsigned short h) {
    unsigned u = ((unsigned)h) << 16;
    return __builtin_bit_cast(float, u);
}

// ---------------------------------------------------------------------------
__global__ void init_gather(const float* __restrict__ x,
                            const int* __restrict__ idx,
                            float* __restrict__ cent,
                            float* __restrict__ csq) {
    int k = blockIdx.x;
    int d = threadIdx.x;
    float v = x[(size_t)idx[k] * D + d];
    cent[k * D + d] = v;
    float s = v * v;
    #pragma unroll
    for (int off = 32; off > 0; off >>= 1) s += __shfl_down(s, off);
    if (d == 0) csq[k] = s;
}

// ---------------------------------------------------------------------------
// score -> argmin (+ exact fp32 refine on near-ties). Same structure as
// rounds 6-12; EPS tightened per the 3e-4 approx-error bound.
__device__ __forceinline__ int resolve_bk(
        const f32x4 (&acc)[16], const float* __restrict__ s_csq,
        const float* __restrict__ cent, const float* __restrict__ xr,
        int g4) {
    // pass 1: global approx min
    float gmin = 3.4e38f;
    int gidx = 0;
    #pragma unroll
    for (int t = 0; t < 16; ++t) {
        f32x4 q = *(const f32x4*)&s_csq[t * 16 + (g4 << 2)];
        #pragma unroll
        for (int r = 0; r < 4; ++r) {
            float sc = acc[t][r] + q[r];
            int m = t * 16 + (g4 << 2) + r;
            if (sc < gmin) { gmin = sc; gidx = m; }
        }
    }
    #pragma unroll
    for (int off = 16; off <= 32; off <<= 1) {
        float so = __shfl_xor(gmin, off);
        int io = __shfl_xor(gidx, off);
        if (so < gmin || (so == gmin && io < gidx)) { gmin = so; gidx = io; }
    }
    // pass 2: candidate mask vs FINAL min
    unsigned long long cmask = 0;
    #pragma unroll
    for (int t = 0; t < 16; ++t) {
        f32x4 q = *(const f32x4*)&s_csq[t * 16 + (g4 << 2)];
        #pragma unroll
        for (int r = 0; r < 4; ++r) {
            float sc = acc[t][r] + q[r];
            if (sc <= gmin + EPS) cmask |= 1ull << (t * 4 + r);
        }
    }
    int nb_ = __popcll(cmask);
    nb_ += __shfl_xor(nb_, 16);
    nb_ += __shfl_xor(nb_, 32);

    int bk = gidx;
    if (__any(nb_ >= 2)) {
        float xsq = 0.0f;
        #pragma unroll
        for (int d = 0; d < D; ++d) xsq += xr[d] * xr[d];
        float eb = 3.4e38f;
        int em = 0x7fffffff;
        unsigned long long mm = cmask;
        while (mm) {
            int b = __ffsll((unsigned long long)mm) - 1;
            mm &= mm - 1;
            int m = ((b >> 2) << 4) + (g4 << 2) + (b & 3);
            const float* cr = cent + m * D;
            float dot = 0.0f;
            #pragma unroll
            for (int d4 = 0; d4 < D; d4 += 4) {
                float4 c4 = *(const float4*)(cr + d4);
                dot += c4.x * xr[d4 + 0];
                dot += c4.y * xr[d4 + 1];
                dot += c4.z * xr[d4 + 2];
                dot += c4.w * xr[d4 + 3];
            }
            float es = xsq - 2.0f * dot + s_csq[m];
            if (es < eb || (es == eb && m < em)) { eb = es; em = m; }
        }
        #pragma unroll
        for (int off = 16; off <= 32; off <<= 1) {
            float so = __shfl_xor(eb, off);
            int io = __shfl_xor(em, off);
            if (so < eb || (so == eb && io < em)) { eb = so; em = io; }
        }
        bk = em;
    }
    return bk;
}

// ---------------------------------------------------------------------------
// fused assign (MFMA + exact refine) + owner-lane LDS accumulate.
// chi/clo LDS layout: [8 k-chunks][256 cents][8 elems] bf16 of (-2*c).
__global__ __launch_bounds__(BLOCK, 4) void assign_mfma(
        const float* __restrict__ x,
        const float* __restrict__ cent,
        const float* __restrict__ csq_g,
        float* __restrict__ parts,
        int N, int ppb) {
    extern __shared__ char smem[];
    short* chi = (short*)smem;                       // 16384 shorts
    short* clo = chi + 16384;                        // 16384 shorts
    float* s_csq = (float*)(clo + 16384);            // 256
    float* s_sums = s_csq + 256;                     // 256*SPAD
    float* s_cnt = s_sums + 256 * SPAD;              // 256

    const int tid = threadIdx.x;

    // ---- stage centroids as -2c hi/lo bf16; zero LDS partials ----
    for (int i = tid; i < (K * D) / 4; i += BLOCK) {
        float4 c4 = ((const float4*)cent)[i];
        int elem = i * 4;
        int m = elem >> 6;
        int k0 = elem & 63;
        int g = k0 >> 3, e0 = k0 & 7;
        float cv[4] = {c4.x, c4.y, c4.z, c4.w};
        short4v hv, lv;
        #pragma unroll
        for (int j = 0; j < 4; ++j) {
            float v = -2.0f * cv[j];
            unsigned short h = f2bf(v);
            hv[j] = (short)h;
            lv[j] = (short)f2bf(v - bf2f(h));
        }
        int dst = (g * 256 + m) * 8 + e0;
        *(short4v*)&chi[dst] = hv;
        *(short4v*)&clo[dst] = lv;
    }
    if (tid < K) s_csq[tid] = csq_g[tid];
    for (int i = tid; i < 256 * SPAD; i += BLOCK) s_sums[i] = 0.0f;
    if (tid < K) s_cnt[tid] = 0.0f;
    __syncthreads();

    const int wv = tid >> 6;          // 0..15
    const int lane = tid & 63;
    const int c15 = lane & 15;        // point-in-group / cent-row-in-tile
    const int g4 = lane >> 4;         // k-chunk group / cent quadrant

    const int base = blockIdx.x * ppb;
    int lim = base + ppb;
    if (lim > N) lim = N;
    const int ngroups = (lim > base) ? ((lim - base + 15) >> 4) : 0;

    #pragma unroll 1
    for (int g0 = wv; g0 < ngroups; g0 += 16) {
        int prow = base + g0 * 16 + c15;
        const bool vA = prow < lim;
        const float* xr = x + (size_t)(vA ? prow : (lim - 1)) * D;

        // ---- this lane's 16 dims of its point + hi/lo bf16 fragments ----
        float xf[16];
        bf16x8 bh[2], bl[2];
        #pragma unroll
        for (int s = 0; s < 2; ++s) {
            const float4* pa = (const float4*)(xr + s * 32 + g4 * 8);
            float4 a0 = pa[0], a1 = pa[1];
            xf[s * 8 + 0] = a0.x; xf[s * 8 + 1] = a0.y;
            xf[s * 8 + 2] = a0.z; xf[s * 8 + 3] = a0.w;
            xf[s * 8 + 4] = a1.x; xf[s * 8 + 5] = a1.y;
            xf[s * 8 + 6] = a1.z; xf[s * 8 + 7] = a1.w;
        }
        #pragma unroll
        for (int s = 0; s < 2; ++s) {
            #pragma unroll
            for (int e = 0; e < 8; ++e) {
                float va = xf[s * 8 + e];
                unsigned short ha = f2bf(va);
                bh[s][e] = (short)ha;
                bl[s][e] = (short)f2bf(va - bf2f(ha));
            }
        }

        // ---- 16 cent-tiles of MFMA ----
        f32x4 acc[16];
        #pragma unroll
        for (int t = 0; t < 16; ++t) {
            f32x4 z = {0.f, 0.f, 0.f, 0.f};
            acc[t] = z;
            #pragma unroll
            for (int s = 0; s < 2; ++s) {
                int ai = (((s * 4 + g4) * 256) + t * 16 + c15) * 8;
                bf16x8 ah = *(const bf16x8*)&chi[ai];
                bf16x8 al = *(const bf16x8*)&clo[ai];
                acc[t] = __builtin_amdgcn_mfma_f32_16x16x32_bf16(ah, bh[s], acc[t], 0, 0, 0);
                acc[t] = __builtin_amdgcn_mfma_f32_16x16x32_bf16(ah, bl[s], acc[t], 0, 0, 0);
                acc[t] = __builtin_amdgcn_mfma_f32_16x16x32_bf16(al, bh[s], acc[t], 0, 0, 0);
            }
        }

        // ---- argmin (+refine), then owner-lane accumulate to LDS ----
        int bk = resolve_bk(acc, s_csq, cent, xr, g4);
        if (vA) {
            #pragma unroll
            for (int s = 0; s < 2; ++s) {
                #pragma unroll
                for (int e = 0; e < 8; ++e)
                    atomicAdd(&s_sums[bk * SPAD + s * 32 + g4 * 8 + e],
                              xf[s * 8 + e]);
            }
            if (g4 == 0) atomicAdd(&s_cnt[bk], 1.0f);
        }
    }

    __syncthreads();
    // ---- flush block partials (unpad) ----
    float* part = parts + (size_t)blockIdx.x * PART_STRIDE;
    for (int i = tid; i < K * D; i += BLOCK) {
        int k = i >> 6, d = i & 63;
        part[i] = s_sums[k * SPAD + d];
    }
    if (tid < K) part[K * D + tid] = s_cnt[tid];
}

// ---------------------------------------------------------------------------
// fused reduce + finalize: one cent per block, 256 threads (4 slices x 64 dims)
__global__ void finalize2(float* __restrict__ cent,
                          const float* __restrict__ parts,
                          float* __restrict__ csq_g,
                          int nb) {
    __shared__ float tmp[4][64];
    __shared__ float tcnt[4];
    int k = blockIdx.x;
    int sl = threadIdx.x >> 6;
    int d = threadIdx.x & 63;
    float s = 0.0f, c = 0.0f;
    for (int b = sl; b < nb; b += 4) {
        const float* pb = parts + (size_t)b * PART_STRIDE;
        s += pb[k * D + d];
        c += pb[K * D + k];
    }
    tmp[sl][d] = s;
    if (d == 0) tcnt[sl] = c;
    __syncthreads();
    if (sl == 0) {
        float st = tmp[0][d] + tmp[1][d] + tmp[2][d] + tmp[3][d];
        float ct = tcnt[0] + tcnt[1] + tcnt[2] + tcnt[3];
        float oldc = cent[k * D + d];
        float nc = (ct > 0.0f) ? (st / ct) : oldc;
        cent[k * D + d] = nc;
        float v = nc * nc;
        #pragma unroll
        for (int off = 32; off > 0; off >>= 1) v += __shfl_down(v, off);
        if (d == 0) csq_g[k] = v;
    }
}

// ---------------------------------------------------------------------------
extern "C" void kernel_launch(void* const* d_in, const int* in_sizes, int n_in,
                              void* d_out, int out_size, void* d_ws, size_t ws_size,
                              hipStream_t stream) {
    const float* x = (const float*)d_in[0];
    const int* init_idx = (const int*)d_in[1];

    int N = in_sizes[0] / D;

    float* cent = (float*)d_out;

    // ws layout: parts[nb][PART_STRIDE] | csq[K]
    int nb = NB_MAX;
    size_t need = ((size_t)NB_MAX * PART_STRIDE + K) * sizeof(float);
    if (ws_size < need) {
        size_t avail = (ws_size > (size_t)K * sizeof(float))
                           ? ws_size - (size_t)K * sizeof(float) : 0;
        nb = (int)(avail / (PART_STRIDE * sizeof(float)));
        if (nb < 1) nb = 1;
    }
    float* parts = (float*)d_ws;
    float* csq = parts + (size_t)nb * PART_STRIDE;

    hipFuncSetAttribute(reinterpret_cast<const void*>(assign_mfma),
                        hipFuncAttributeMaxDynamicSharedMemorySize, SMEM_BYTES);

    init_gather<<<dim3(K), dim3(64), 0, stream>>>(x, init_idx, cent, csq);

    int ppb = (N + nb - 1) / nb;
    for (int it = 0; it < ITERS; ++it) {
        assign_mfma<<<dim3(nb), dim3(BLOCK), SMEM_BYTES, stream>>>(
            x, cent, csq, parts, N, ppb);
        finalize2<<<dim3(K), dim3(256), 0, stream>>>(cent, parts, csq, nb);
    }
}